// Round 1
// baseline (307.105 us; speedup 1.0000x reference)
//
#include <hip/hip_runtime.h>
#include <hip/hip_bf16.h>
#include <cstdint>

#define B_ 4
#define C_ 256
#define N_ 4096
#define D_ 32

typedef __attribute__((ext_vector_type(8))) short bf16x8;
typedef __attribute__((ext_vector_type(4))) float f32x4;
typedef __attribute__((ext_vector_type(4))) int i32x4;

__device__ inline unsigned short f2bf(float f) {
    union { float f; uint32_t u; } v; v.f = f;
    uint32_t u = v.u;
    u += 0x7FFFu + ((u >> 16) & 1u);   // round-to-nearest-even
    return (unsigned short)(u >> 16);
}

// ---------------------------------------------------------------------------
// Projection kernel: Qt[b][n][d], Kt[b][n][d] (bf16, n-major so MFMA frags are
// contiguous 16B/lane), V[b][c][n] (bf16). fp32 vector GEMM, LDS-tiled.
// grid: (N/64, 5, B). g=0 -> rows 0..31 = Wq, 32..63 = Wk; g=1..4 -> Wv chunks.
// ---------------------------------------------------------------------------
__global__ __launch_bounds__(256) void proj_kernel(
    const float* __restrict__ x,
    const float* __restrict__ Wq, const float* __restrict__ bq,
    const float* __restrict__ Wk, const float* __restrict__ bk,
    const float* __restrict__ Wv, const float* __restrict__ bv,
    unsigned short* __restrict__ Qt, unsigned short* __restrict__ Kt,
    unsigned short* __restrict__ V)
{
    __shared__ float xs[64][65];
    __shared__ float wsm[64][65];
    const int t  = threadIdx.x;
    const int n0 = blockIdx.x * 64;
    const int g  = blockIdx.y;
    const int b  = blockIdx.z;

    const int tn = t & 15;   // n sub-block (4 n's each)
    const int tr = t >> 4;   // row sub (rows tr, tr+16, tr+32, tr+48)

    float acc[4][4] = {};

    for (int ch = 0; ch < 4; ++ch) {
        const int c0 = ch * 64;
        __syncthreads();
        // load x tile [64 c][64 n] — coalesced along n
        #pragma unroll
        for (int rep = 0; rep < 16; ++rep) {
            int li = rep * 256 + t;
            int cc = li >> 6, nn = li & 63;
            xs[cc][nn] = x[(size_t)(b * C_ + c0 + cc) * N_ + n0 + nn];
        }
        // load weight tile [64 rows][64 c]
        #pragma unroll
        for (int rep = 0; rep < 16; ++rep) {
            int li = rep * 256 + t;
            int r = li >> 6, cc = li & 63;
            float wv;
            if (g == 0) {
                wv = (r < 32) ? Wq[r * C_ + c0 + cc]
                              : Wk[(r - 32) * C_ + c0 + cc];
            } else {
                wv = Wv[((g - 1) * 64 + r) * C_ + c0 + cc];
            }
            wsm[r][cc] = wv;
        }
        __syncthreads();
        #pragma unroll 8
        for (int cc = 0; cc < 64; ++cc) {
            float wv[4], xv[4];
            #pragma unroll
            for (int i = 0; i < 4; ++i) wv[i] = wsm[tr + 16 * i][cc];
            #pragma unroll
            for (int j = 0; j < 4; ++j) xv[j] = xs[cc][tn * 4 + j];
            #pragma unroll
            for (int i = 0; i < 4; ++i)
                #pragma unroll
                for (int j = 0; j < 4; ++j)
                    acc[i][j] += wv[i] * xv[j];
        }
    }

    #pragma unroll
    for (int i = 0; i < 4; ++i) {
        int r = tr + 16 * i;
        #pragma unroll
        for (int j = 0; j < 4; ++j) {
            int n = n0 + tn * 4 + j;
            if (g == 0) {
                if (r < 32) {
                    Qt[((size_t)b * N_ + n) * D_ + r]        = f2bf(acc[i][j] + bq[r]);
                } else {
                    Kt[((size_t)b * N_ + n) * D_ + (r - 32)] = f2bf(acc[i][j] + bk[r - 32]);
                }
            } else {
                int c = (g - 1) * 64 + r;
                V[((size_t)b * C_ + c) * N_ + n] = f2bf(acc[i][j] + bv[c]);
            }
        }
    }
}

// ---------------------------------------------------------------------------
// Flash attention kernel. grid: (N/64, B), 256 threads = 4 waves.
// Wave w owns queries [n0 + 16w, +16), all 256 channels.
// Per 64-key tile: 4 QK MFMAs, online softmax, 32 PV MFMAs.
// V tile staged in LDS with XOR swizzle; P through per-wave LDS scratch.
// ---------------------------------------------------------------------------
__global__ __launch_bounds__(256) void attn_kernel(
    const unsigned short* __restrict__ Qt, const unsigned short* __restrict__ Kt,
    const unsigned short* __restrict__ V,  const float* __restrict__ x,
    const float* __restrict__ gamma, float* __restrict__ out)
{
    __shared__ __align__(16) char smem[32768 + 8192];  // Vs 32KB + 4x2KB P
    char* Vs = smem;
    const int t  = threadIdx.x;
    const int w  = t >> 6;
    const int l  = t & 63;
    const int lg = l >> 4;   // lane group 0..3
    const int ll = l & 15;
    const int n0 = blockIdx.x * 64;
    const int b  = blockIdx.y;
    char* Pw = smem + 32768 + w * 2048;

    // Q A-fragment: A[i=ll][d=8*lg+e]  (16B contiguous from Qt)
    const int qrow = n0 + w * 16 + ll;
    const bf16x8 qfrag =
        *reinterpret_cast<const bf16x8*>(Qt + ((size_t)b * N_ + qrow) * D_ + 8 * lg);

    f32x4 acc[16];
    #pragma unroll
    for (int i = 0; i < 16; ++i) acc[i] = (f32x4){0.f, 0.f, 0.f, 0.f};
    float m[4], lsum[4];
    #pragma unroll
    for (int r = 0; r < 4; ++r) { m[r] = -INFINITY; lsum[r] = 0.f; }

    const int cl = t >> 3;     // V-load: channel sub-row
    const int chunk = t & 7;   // V-load: 16B chunk along j

    for (int kt = 0; kt < 64; ++kt) {
        const int j0 = kt * 64;

        // K B-fragments from global: B[d][j] = Kt[j][d], coalesced
        bf16x8 kfrag[4];
        #pragma unroll
        for (int s = 0; s < 4; ++s)
            kfrag[s] = *reinterpret_cast<const bf16x8*>(
                Kt + ((size_t)b * N_ + j0 + s * 16 + ll) * D_ + 8 * lg);

        __syncthreads();  // prior PV reads of Vs done
        // cooperative V tile load [256 c][64 j] bf16, XOR-swizzled
        #pragma unroll
        for (int pass = 0; pass < 8; ++pass) {
            int c = pass * 32 + cl;
            i32x4 val = *reinterpret_cast<const i32x4*>(
                V + ((size_t)b * C_ + c) * N_ + j0 + chunk * 8);
            *reinterpret_cast<i32x4*>(Vs + c * 128 + ((chunk * 16) ^ ((c & 7) << 4))) = val;
        }

        // S = Q^T K  (16 queries x 64 keys per wave)
        f32x4 sfrag[4];
        const f32x4 zero4 = {0.f, 0.f, 0.f, 0.f};
        #pragma unroll
        for (int s = 0; s < 4; ++s)
            sfrag[s] = __builtin_amdgcn_mfma_f32_16x16x32_bf16(qfrag, kfrag[s], zero4, 0, 0, 0);

        __syncthreads();  // Vs ready

        // ---- online softmax (C/D layout: row = lg*4+r, col = ll) ----
        float tmax[4];
        #pragma unroll
        for (int r = 0; r < 4; ++r)
            tmax[r] = fmaxf(fmaxf(sfrag[0][r], sfrag[1][r]),
                            fmaxf(sfrag[2][r], sfrag[3][r]));
        #pragma unroll
        for (int off = 1; off < 16; off <<= 1)
            #pragma unroll
            for (int r = 0; r < 4; ++r)
                tmax[r] = fmaxf(tmax[r], __shfl_xor(tmax[r], off));

        float scale[4];
        #pragma unroll
        for (int r = 0; r < 4; ++r) {
            float mn = fmaxf(m[r], tmax[r]);
            scale[r] = __expf(m[r] - mn);
            m[r] = mn;
            lsum[r] *= scale[r];
        }
        float rsum[4] = {0.f, 0.f, 0.f, 0.f};
        #pragma unroll
        for (int s = 0; s < 4; ++s)
            #pragma unroll
            for (int r = 0; r < 4; ++r) {
                float p = __expf(sfrag[s][r] - m[r]);
                sfrag[s][r] = p;
                rsum[r] += p;
            }
        #pragma unroll
        for (int off = 1; off < 16; off <<= 1)
            #pragma unroll
            for (int r = 0; r < 4; ++r)
                rsum[r] += __shfl_xor(rsum[r], off);
        #pragma unroll
        for (int r = 0; r < 4; ++r) lsum[r] += rsum[r];
        #pragma unroll
        for (int i = 0; i < 16; ++i)
            #pragma unroll
            for (int r = 0; r < 4; ++r)
                acc[i][r] *= scale[r];

        // ---- P -> per-wave LDS (bf16, swizzled), then A-fragments ----
        #pragma unroll
        for (int s = 0; s < 4; ++s)
            #pragma unroll
            for (int r = 0; r < 4; ++r) {
                int row = lg * 4 + r;
                int byte = row * 128 + ((s * 32 + 2 * ll) ^ ((row & 7) << 4));
                *reinterpret_cast<unsigned short*>(Pw + byte) = f2bf(sfrag[s][r]);
            }
        bf16x8 pfrag[2];
        #pragma unroll
        for (int h = 0; h < 2; ++h) {
            int byte = ll * 128 + (((h * 64) + 16 * lg) ^ ((ll & 7) << 4));
            pfrag[h] = *reinterpret_cast<const bf16x8*>(Pw + byte);
        }

        // ---- PV: acc[ct] += P(16x32j) @ V^T(32j x 16c) ----
        #pragma unroll
        for (int ct = 0; ct < 16; ++ct) {
            int c = ct * 16 + ll;
            #pragma unroll
            for (int h = 0; h < 2; ++h) {
                bf16x8 vfrag = *reinterpret_cast<const bf16x8*>(
                    Vs + c * 128 + (((h * 64) + 16 * lg) ^ ((c & 7) << 4)));
                acc[ct] = __builtin_amdgcn_mfma_f32_16x16x32_bf16(pfrag[h], vfrag, acc[ct], 0, 0, 0);
            }
        }
    }

    // ---- epilogue: out = gamma * (acc/l) + x, transposed via LDS ----
    const float g0 = gamma[0];
    float* Ot = reinterpret_cast<float*>(smem);  // [64][65] fp32, reuses Vs
    for (int cg = 0; cg < 4; ++cg) {
        __syncthreads();
        #pragma unroll
        for (int i = 0; i < 4; ++i) {
            int ct = cg * 4 + i;
            #pragma unroll
            for (int r = 0; r < 4; ++r) {
                int crow = i * 16 + ll;            // channel within 64-chunk
                int ncol = w * 16 + lg * 4 + r;    // query within 64-block
                Ot[crow * 65 + ncol] = acc[ct][r] / lsum[r];
            }
        }
        __syncthreads();
        #pragma unroll
        for (int rep = 0; rep < 16; ++rep) {
            int li = rep * 256 + t;
            int crow = li >> 6, nn = li & 63;
            size_t gi = ((size_t)b * C_ + cg * 64 + crow) * N_ + n0 + nn;
            out[gi] = g0 * Ot[crow * 65 + nn] + x[gi];
        }
    }
}

extern "C" void kernel_launch(void* const* d_in, const int* in_sizes, int n_in,
                              void* d_out, int out_size, void* d_ws, size_t ws_size,
                              hipStream_t stream) {
    const float* x     = (const float*)d_in[0];
    const float* Wq    = (const float*)d_in[1];
    const float* bq    = (const float*)d_in[2];
    const float* Wk    = (const float*)d_in[3];
    const float* bk    = (const float*)d_in[4];
    const float* Wv    = (const float*)d_in[5];
    const float* bv    = (const float*)d_in[6];
    const float* gamma = (const float*)d_in[7];
    float* out = (float*)d_out;

    char* ws = (char*)d_ws;
    unsigned short* Qt = (unsigned short*)(ws);                 // 1 MB
    unsigned short* Kt = (unsigned short*)(ws + (1u << 20));    // 1 MB
    unsigned short* V  = (unsigned short*)(ws + (2u << 20));    // 8 MB

    proj_kernel<<<dim3(N_ / 64, 5, B_), 256, 0, stream>>>(
        x, Wq, bq, Wk, bk, Wv, bv, Qt, Kt, V);
    attn_kernel<<<dim3(N_ / 64, B_), 256, 0, stream>>>(
        Qt, Kt, V, x, gamma, out);
}